// Round 1
// baseline (707.911 us; speedup 1.0000x reference)
//
#include <hip/hip_runtime.h>
#include <stdint.h>

#define B_N 512
#define E_N 1024
#define ML_N 50
#define V_N 50000

typedef __bf16 bf16_t;
typedef __bf16 bf16x8 __attribute__((ext_vector_type(8)));
typedef float f32x4 __attribute__((ext_vector_type(4)));

__device__ __forceinline__ uint16_t f2bf(float f) {
    union { float f; uint32_t u; } v; v.f = f;
    return (uint16_t)((v.u + 0x7FFFu + ((v.u >> 16) & 1u)) >> 16);  // RNE
}
__device__ __forceinline__ uint32_t packbf2(float lo, float hi) {
    return (uint32_t)f2bf(lo) | ((uint32_t)f2bf(hi) << 16);
}
__device__ __forceinline__ void load_lds16(const void* g, void* l) {
    __builtin_amdgcn_global_load_lds((const __attribute__((address_space(1))) void*)g,
                                     (__attribute__((address_space(3))) void*)l, 16, 0, 0);
}

// ---------------------------------------------------------------------------
// K0: classify padded_positions dtype: 0 = int32 {0,1}, 1 = float32 {0,1.0f},
// 2 = byte. Reads first 25600 bytes (in-bounds under every interpretation).
__global__ __launch_bounds__(256) void detect_mask_mode(const uint32_t* __restrict__ mp,
                                                        int* __restrict__ mode_out) {
    __shared__ int s_int_ok, s_flt_ok;
    if (threadIdx.x == 0) { s_int_ok = 1; s_flt_ok = 1; }
    __syncthreads();
    int int_ok = 1, flt_ok = 1;
    for (int i = threadIdx.x; i < 6400; i += 256) {
        uint32_t v = mp[i];
        if (!(v == 0u || v == 1u)) int_ok = 0;
        if (!(v == 0u || v == 0x3F800000u)) flt_ok = 0;
    }
    if (!int_ok) atomicAnd(&s_int_ok, 0);
    if (!flt_ok) atomicAnd(&s_flt_ok, 0);
    __syncthreads();
    if (threadIdx.x == 0) *mode_out = s_int_ok ? 0 : (s_flt_ok ? 1 : 2);
}

// ---------------------------------------------------------------------------
// K1: attention (fp32) + embed gather. One block per batch row, 256 threads.
__global__ __launch_bounds__(256) void attn_kernel(
    const float* __restrict__ enc,   // [B][ML][E]
    const float* __restrict__ h0,    // [B][E]
    const void* __restrict__ maskp,  // [B][ML] (dtype per mode)
    const int* __restrict__ mode_p,
    const int* __restrict__ ts,      // [B]
    const float* __restrict__ emb,   // [V][E]
    float* __restrict__ ctx_f,       // ws [B][E] fp32
    bf16_t* __restrict__ a_lstm)     // ws [B][2E] bf16: [words | contexts]
{
    __shared__ float hs[E_N];
    __shared__ float en[64];
    __shared__ float normed[64];
    int b = blockIdx.x;
    int tid = threadIdx.x;
    int lane = tid & 63, wv = tid >> 6;

    for (int i = tid; i < E_N / 4; i += 256)
        ((float4*)hs)[i] = ((const float4*)(h0 + (size_t)b * E_N))[i];
    __syncthreads();

    const float* encb = enc + (size_t)b * ML_N * E_N;
    // energies: wave wv handles l = wv, wv+4, ...
    for (int l = wv; l < ML_N; l += 4) {
        const float4* row = (const float4*)(encb + l * E_N);
        float acc = 0.f;
        #pragma unroll
        for (int t = 0; t < 4; t++) {
            float4 e4 = row[lane + 64 * t];
            float4 h4 = ((const float4*)hs)[lane + 64 * t];
            acc += e4.x * h4.x + e4.y * h4.y + e4.z * h4.z + e4.w * h4.w;
        }
        #pragma unroll
        for (int off = 32; off > 0; off >>= 1) acc += __shfl_down(acc, off, 64);
        if (lane == 0) en[l] = acc;
    }
    __syncthreads();

    // masked softmax (unmasked softmax -> zero padded -> renorm == masked softmax)
    if (wv == 0) {
        int mode = *mode_p;
        float e = (lane < ML_N) ? en[lane] : -1e30f;
        int pad = 0;
        if (lane < ML_N) {
            int mi = b * ML_N + lane;
            if (mode == 0)      pad = (((const int*)maskp)[mi] != 0);
            else if (mode == 1) pad = (((const float*)maskp)[mi] != 0.0f);
            else                pad = (((const unsigned char*)maskp)[mi] != 0);
        }
        float m = e;
        #pragma unroll
        for (int off = 32; off > 0; off >>= 1) m = fmaxf(m, __shfl_down(m, off, 64));
        m = __shfl(m, 0, 64);
        float x = (lane < ML_N && !pad) ? __expf(e - m) : 0.f;
        float s = x;
        #pragma unroll
        for (int off = 32; off > 0; off >>= 1) s += __shfl_down(s, off, 64);
        s = __shfl(s, 0, 64);
        normed[lane] = x / s;
    }
    __syncthreads();

    // contexts[e] = sum_l normed[l] * enc[b][l][e] ; thread handles 4 elems
    float4 acc = {0.f, 0.f, 0.f, 0.f};
    for (int l = 0; l < ML_N; l++) {
        float w = normed[l];
        float4 e4 = ((const float4*)(encb + l * E_N))[tid];
        acc.x += w * e4.x; acc.y += w * e4.y; acc.z += w * e4.z; acc.w += w * e4.w;
    }
    ((float4*)(ctx_f + (size_t)b * E_N))[tid] = acc;
    ushort4 cb; cb.x = f2bf(acc.x); cb.y = f2bf(acc.y); cb.z = f2bf(acc.z); cb.w = f2bf(acc.w);
    ((ushort4*)(a_lstm + (size_t)b * 2048 + E_N))[tid] = cb;

    // embed gather -> bf16 words
    int wid = ts[b];
    float4 w4 = ((const float4*)(emb + (size_t)wid * E_N))[tid];
    ushort4 wb; wb.x = f2bf(w4.x); wb.y = f2bf(w4.y); wb.z = f2bf(w4.z); wb.w = f2bf(w4.w);
    ((ushort4*)(a_lstm + (size_t)b * 2048))[tid] = wb;
}

// ---------------------------------------------------------------------------
// bf16 MFMA GEMM: out[M][N] = A(bf16)[M][K] @ W^T + bias1 (+bias2)
// W rows: k < K1 -> W1[n][k], else W2[n][k-K1]. W is fp32, converted to bf16
// during LDS staging. 128x128 tile, BK=32, 4 waves of 64x64 each.
__global__ __launch_bounds__(256) void gemm_bf16(
    const bf16_t* __restrict__ A, const float* __restrict__ W1,
    const float* __restrict__ W2, const float* __restrict__ bias1,
    const float* __restrict__ bias2, float* __restrict__ out,
    int M, int N, int K, int K1)
{
    __shared__ __align__(16) bf16_t As[128 * 32];   // linear, required by global_load_lds
    __shared__ __align__(16) bf16_t Bs[128 * 40];   // padded stride 40 elems (80B)

    int tid = threadIdx.x;
    int lane = tid & 63, wv = tid >> 6;
    int quad = lane >> 4, l16 = lane & 15;
    int n0 = blockIdx.x * 128, m0 = blockIdx.y * 128;
    int wm = (wv >> 1) * 64, wn = (wv & 1) * 64;

    f32x4 acc[4][4];
    #pragma unroll
    for (int a = 0; a < 4; a++)
        #pragma unroll
        for (int b2 = 0; b2 < 4; b2++) { f32x4 z = {0.f,0.f,0.f,0.f}; acc[a][b2] = z; }

    int brow = tid >> 1, bhalf = tid & 1;
    int gn_l = n0 + brow; if (gn_l >= N) gn_l = N - 1;   // clamp (dup loads ok)
    int c0i = wv * 64 + lane, c1i = 256 + wv * 64 + lane;

    for (int k0 = 0; k0 < K; k0 += 32) {
        __syncthreads();
        // --- stage A (bf16) via async global->LDS, 16B/lane ---
        load_lds16(A + (size_t)(m0 + (c0i >> 2)) * K + k0 + (c0i & 3) * 8, As + wv * 512);
        load_lds16(A + (size_t)(m0 + (c1i >> 2)) * K + k0 + (c1i & 3) * 8, As + 2048 + wv * 512);
        // --- stage B: 16 fp32 per thread -> 16 bf16 -> LDS ---
        int kk = k0 + bhalf * 16;
        const float* wrow = (kk < K1) ? (W1 + (size_t)gn_l * K1 + kk)
                                      : (W2 + (size_t)gn_l * K1 + (kk - K1));
        float4 f0 = ((const float4*)wrow)[0];
        float4 f1 = ((const float4*)wrow)[1];
        float4 f2 = ((const float4*)wrow)[2];
        float4 f3 = ((const float4*)wrow)[3];
        uint4 p0, p1;
        p0.x = packbf2(f0.x, f0.y); p0.y = packbf2(f0.z, f0.w);
        p0.z = packbf2(f1.x, f1.y); p0.w = packbf2(f1.z, f1.w);
        p1.x = packbf2(f2.x, f2.y); p1.y = packbf2(f2.z, f2.w);
        p1.z = packbf2(f3.x, f3.y); p1.w = packbf2(f3.z, f3.w);
        uint4* bsp = (uint4*)(Bs + brow * 40 + bhalf * 16);
        bsp[0] = p0; bsp[1] = p1;
        __syncthreads();

        // --- compute: 8 ds_read_b128 + 16 MFMA per wave ---
        bf16x8 af[4], bfr[4];
        #pragma unroll
        for (int i = 0; i < 4; i++) {
            af[i]  = *(const bf16x8*)(As + (wm + i * 16 + l16) * 32 + quad * 8);
            bfr[i] = *(const bf16x8*)(Bs + (wn + i * 16 + l16) * 40 + quad * 8);
        }
        #pragma unroll
        for (int mi = 0; mi < 4; mi++)
            #pragma unroll
            for (int ni = 0; ni < 4; ni++)
                acc[mi][ni] = __builtin_amdgcn_mfma_f32_16x16x32_bf16(
                    af[mi], bfr[ni], acc[mi][ni], 0, 0, 0);
    }

    // epilogue: D[row=quad*4+r][col=l16] per 16x16 tile (m89-verified layout)
    #pragma unroll
    for (int mi = 0; mi < 4; mi++) {
        int gm = m0 + wm + mi * 16 + quad * 4;
        #pragma unroll
        for (int ni = 0; ni < 4; ni++) {
            int gn = n0 + wn + ni * 16 + l16;
            if (gn < N) {
                float bs = bias1[gn];
                if (bias2) bs += bias2[gn];
                #pragma unroll
                for (int r = 0; r < 4; r++)
                    out[(size_t)(gm + r) * N + gn] = acc[mi][ni][r] + bs;
            }
        }
    }
}

// ---------------------------------------------------------------------------
// K3: LSTM cell elementwise. gates[b][4096] (i,f,g,o), prior cell/hidden = ctx.
__global__ __launch_bounds__(256) void lstm_cell(
    const float* __restrict__ gates, const float* __restrict__ ctx,
    float* __restrict__ h_out, float* __restrict__ c_out,
    uint16_t* __restrict__ h_bf)
{
    int idx = blockIdx.x * 256 + threadIdx.x;   // 0..B*E-1
    int b = idx >> 10, e = idx & 1023;
    const float* g = gates + ((size_t)b << 12);
    float iv = g[e], fv = g[e + 1024], gv = g[e + 2048], ov = g[e + 3072];
    iv = 1.f / (1.f + __expf(-iv));
    fv = 1.f / (1.f + __expf(-fv));
    gv = tanhf(gv);
    ov = 1.f / (1.f + __expf(-ov));
    float c = fv * ctx[idx] + iv * gv;
    float h = ov * tanhf(c);
    c_out[idx] = c;
    h_out[idx] = h;
    h_bf[idx] = f2bf(h);
}

// ---------------------------------------------------------------------------
extern "C" void kernel_launch(void* const* d_in, const int* in_sizes, int n_in,
                              void* d_out, int out_size, void* d_ws, size_t ws_size,
                              hipStream_t stream)
{
    const int*   ts     = (const int*)d_in[0];
    const float* enc    = (const float*)d_in[1];
    const float* h0     = (const float*)d_in[2];
    // d_in[3] = c0: unused by the reference math
    const void*  mask   = d_in[4];
    // d_in[5] = max_len scalar (== 50, hard-coded)
    const float* emb    = (const float*)d_in[6];
    const float* w_ih   = (const float*)d_in[7];
    const float* w_hh   = (const float*)d_in[8];
    const float* b_ih   = (const float*)d_in[9];
    const float* b_hh   = (const float*)d_in[10];
    const float* w_proj = (const float*)d_in[11];
    const float* b_proj = (const float*)d_in[12];
    float* out = (float*)d_out;

    // ws layout: [mode int | ctx_f 2MB | a_lstm 2MB | h_bf 1MB]  (~5.3 MB)
    char* ws = (char*)d_ws;
    int*      mode   = (int*)ws;
    float*    ctx_f  = (float*)(ws + 256);
    bf16_t*   a_lstm = (bf16_t*)(ws + 256 + ((size_t)2 << 20));
    uint16_t* h_bf   = (uint16_t*)(ws + 256 + ((size_t)4 << 20));
    // gates scratch (8 MB) lives in the logits region of d_out; the projection
    // GEMM overwrites it afterwards (stream-ordered).
    float* gates = out;

    float* h_out = out + (size_t)B_N * V_N;            // 25,600,000
    float* c_out = h_out + (size_t)B_N * E_N;          // +524,288

    detect_mask_mode<<<1, 256, 0, stream>>>((const uint32_t*)mask, mode);
    attn_kernel<<<B_N, 256, 0, stream>>>(enc, h0, mask, mode, ts, emb, ctx_f, a_lstm);
    // gates = [words|ctx] @ [w_ih|w_hh]^T + b_ih + b_hh  (M=512,N=4096,K=2048)
    gemm_bf16<<<dim3(4096 / 128, B_N / 128), 256, 0, stream>>>(
        a_lstm, w_ih, w_hh, b_ih, b_hh, gates, B_N, 4096, 2048, 1024);
    lstm_cell<<<(B_N * E_N) / 256, 256, 0, stream>>>(gates, ctx_f, h_out, c_out, h_bf);
    // logits = h_new @ w_proj^T + b_proj  (M=512,N=50000,K=1024)
    gemm_bf16<<<dim3((V_N + 127) / 128, B_N / 128), 256, 0, stream>>>(
        (const bf16_t*)h_bf, w_proj, w_proj, b_proj, nullptr, out, B_N, V_N, 1024, 1024);
}

// Round 2
// 689.900 us; speedup vs baseline: 1.0261x; 1.0261x over previous
//
#include <hip/hip_runtime.h>
#include <stdint.h>

#define B_N 512
#define E_N 1024
#define ML_N 50
#define V_N 50000
#define V_PAD 50048   // 391 * 128

typedef __bf16 bf16_t;
typedef __bf16 bf16x8 __attribute__((ext_vector_type(8)));
typedef float f32x4 __attribute__((ext_vector_type(4)));

__device__ __forceinline__ uint16_t f2bf(float f) {
    union { float f; uint32_t u; } v; v.f = f;
    return (uint16_t)((v.u + 0x7FFFu + ((v.u >> 16) & 1u)) >> 16);  // RNE
}
__device__ __forceinline__ uint32_t packbf2(float lo, float hi) {
    return (uint32_t)f2bf(lo) | ((uint32_t)f2bf(hi) << 16);
}
__device__ __forceinline__ void load_lds16(const void* g, void* l) {
    __builtin_amdgcn_global_load_lds((const __attribute__((address_space(1))) void*)g,
                                     (__attribute__((address_space(3))) void*)l, 16, 0, 0);
}

// ---------------------------------------------------------------------------
// K0: classify padded_positions dtype: 0 = int32 {0,1}, 1 = float32 {0,1.0f},
// 2 = byte. Reads first 25600 bytes (in-bounds under every interpretation).
__global__ __launch_bounds__(256) void detect_mask_mode(const uint32_t* __restrict__ mp,
                                                        int* __restrict__ mode_out) {
    __shared__ int s_int_ok, s_flt_ok;
    if (threadIdx.x == 0) { s_int_ok = 1; s_flt_ok = 1; }
    __syncthreads();
    int int_ok = 1, flt_ok = 1;
    for (int i = threadIdx.x; i < 6400; i += 256) {
        uint32_t v = mp[i];
        if (!(v == 0u || v == 1u)) int_ok = 0;
        if (!(v == 0u || v == 0x3F800000u)) flt_ok = 0;
    }
    if (!int_ok) atomicAnd(&s_int_ok, 0);
    if (!flt_ok) atomicAnd(&s_flt_ok, 0);
    __syncthreads();
    if (threadIdx.x == 0) *mode_out = s_int_ok ? 0 : (s_flt_ok ? 1 : 2);
}

// ---------------------------------------------------------------------------
// Weight conversion: fp32 -> bf16, streaming, 8 elems/thread.
// wcat[n][k], n<4096, k<2048: k<1024 -> w_ih[n][k], else w_hh[n][k-1024]
__global__ __launch_bounds__(256) void convert_cat(const float* __restrict__ w_ih,
                                                   const float* __restrict__ w_hh,
                                                   uint16_t* __restrict__ outp) {
    size_t idx = ((size_t)blockIdx.x * 256 + threadIdx.x) * 8;  // < 4096*2048
    int n = (int)(idx >> 11), k = (int)(idx & 2047);
    const float* src = (k < 1024) ? (w_ih + (size_t)n * 1024 + k)
                                  : (w_hh + (size_t)n * 1024 + (k - 1024));
    float4 a = ((const float4*)src)[0], b = ((const float4*)src)[1];
    uint4 p;
    p.x = packbf2(a.x, a.y); p.y = packbf2(a.z, a.w);
    p.z = packbf2(b.x, b.y); p.w = packbf2(b.z, b.w);
    ((uint4*)(outp + idx))[0] = p;
}

// wproj_bf[V_PAD][1024]; rows >= V_N zero-filled
__global__ __launch_bounds__(256) void convert_proj(const float* __restrict__ w,
                                                    uint16_t* __restrict__ outp) {
    size_t idx = ((size_t)blockIdx.x * 256 + threadIdx.x) * 8;  // < V_PAD*1024
    uint4 p = {0u, 0u, 0u, 0u};
    if (idx < (size_t)V_N * 1024) {
        float4 a = ((const float4*)(w + idx))[0], b = ((const float4*)(w + idx))[1];
        p.x = packbf2(a.x, a.y); p.y = packbf2(a.z, a.w);
        p.z = packbf2(b.x, b.y); p.w = packbf2(b.z, b.w);
    }
    ((uint4*)(outp + idx))[0] = p;
}

// ---------------------------------------------------------------------------
// K1a: energies + masked softmax. One block per batch row; writes normed[b][64].
__global__ __launch_bounds__(256) void energy_kernel(
    const float* __restrict__ enc, const float* __restrict__ h0,
    const void* __restrict__ maskp, const int* __restrict__ mode_p,
    float* __restrict__ normed_ws)   // [B][64]
{
    __shared__ float hs[E_N];
    __shared__ float en[64];
    int b = blockIdx.x;
    int tid = threadIdx.x;
    int lane = tid & 63, wv = tid >> 6;

    for (int i = tid; i < E_N / 4; i += 256)
        ((float4*)hs)[i] = ((const float4*)(h0 + (size_t)b * E_N))[i];
    __syncthreads();

    const float* encb = enc + (size_t)b * ML_N * E_N;
    for (int l = wv; l < ML_N; l += 4) {
        const float4* row = (const float4*)(encb + l * E_N);
        float acc = 0.f;
        #pragma unroll
        for (int t = 0; t < 4; t++) {
            float4 e4 = row[lane + 64 * t];
            float4 h4 = ((const float4*)hs)[lane + 64 * t];
            acc += e4.x * h4.x + e4.y * h4.y + e4.z * h4.z + e4.w * h4.w;
        }
        #pragma unroll
        for (int off = 32; off > 0; off >>= 1) acc += __shfl_down(acc, off, 64);
        if (lane == 0) en[l] = acc;
    }
    __syncthreads();

    if (wv == 0) {
        int mode = *mode_p;
        float e = (lane < ML_N) ? en[lane] : -1e30f;
        int pad = 0;
        if (lane < ML_N) {
            int mi = b * ML_N + lane;
            if (mode == 0)      pad = (((const int*)maskp)[mi] != 0);
            else if (mode == 1) pad = (((const float*)maskp)[mi] != 0.0f);
            else                pad = (((const unsigned char*)maskp)[mi] != 0);
        }
        float m = e;
        #pragma unroll
        for (int off = 32; off > 0; off >>= 1) m = fmaxf(m, __shfl_down(m, off, 64));
        m = __shfl(m, 0, 64);
        float x = (lane < ML_N && !pad) ? __expf(e - m) : 0.f;
        float s = x;
        #pragma unroll
        for (int off = 32; off > 0; off >>= 1) s += __shfl_down(s, off, 64);
        s = __shfl(s, 0, 64);
        normed_ws[b * 64 + lane] = x / s;
    }
}

// K1b: contexts + embed gather. grid (B, 4); block handles 256 e's for one b.
__global__ __launch_bounds__(256) void ctx_kernel(
    const float* __restrict__ enc, const float* __restrict__ normed_ws,
    const int* __restrict__ ts, const float* __restrict__ emb,
    float* __restrict__ ctx_f, bf16_t* __restrict__ a_lstm)
{
    __shared__ float nrm[64];
    int b = blockIdx.x;
    int e = blockIdx.y * 256 + threadIdx.x;
    if (threadIdx.x < 64) nrm[threadIdx.x] = normed_ws[b * 64 + threadIdx.x];
    __syncthreads();

    const float* encb = enc + (size_t)b * ML_N * E_N + e;
    float acc = 0.f;
    #pragma unroll 10
    for (int l = 0; l < ML_N; l++)
        acc += nrm[l] * encb[(size_t)l * E_N];
    ctx_f[(size_t)b * E_N + e] = acc;
    a_lstm[(size_t)b * 2048 + 1024 + e] = (bf16_t)acc;

    int wid = ts[b];
    float wv = emb[(size_t)wid * E_N + e];
    a_lstm[(size_t)b * 2048 + e] = (bf16_t)wv;
}

// ---------------------------------------------------------------------------
// Pure-bf16 MFMA GEMM (m97 structure): out[M][N] = A[M][K] @ Bt[N][K]^T + bias.
// A, Bt bf16; both staged via global_load_lds width-16. 128x128 tile, BK=32.
// Grid: x = m-tile (fast, so m-blocks sharing a Bt tile are temporally
// adjacent -> LLC reuse), y = n-tile.
__global__ __launch_bounds__(256) void gemm_bt(
    const bf16_t* __restrict__ A, const bf16_t* __restrict__ Bt,
    const float* __restrict__ bias1, const float* __restrict__ bias2,
    float* __restrict__ out, int M, int N, int K)
{
    __shared__ __align__(16) bf16_t As[128 * 32];
    __shared__ __align__(16) bf16_t Bs[128 * 32];

    int tid = threadIdx.x;
    int lane = tid & 63, wv = tid >> 6;
    int quad = lane >> 4, l16 = lane & 15;
    int m0 = blockIdx.x * 128, n0 = blockIdx.y * 128;
    int wm = (wv >> 1) * 64, wn = (wv & 1) * 64;

    f32x4 acc[4][4];
    #pragma unroll
    for (int a = 0; a < 4; a++)
        #pragma unroll
        for (int b2 = 0; b2 < 4; b2++) { f32x4 z = {0.f, 0.f, 0.f, 0.f}; acc[a][b2] = z; }

    int c0 = wv * 64 + lane;           // 0..255
    int r0 = c0 >> 2, koff = (c0 & 3) * 8;

    for (int k0 = 0; k0 < K; k0 += 32) {
        __syncthreads();
        load_lds16(A  + (size_t)(m0 + r0) * K + k0 + koff,      As + wv * 512);
        load_lds16(A  + (size_t)(m0 + 64 + r0) * K + k0 + koff, As + 2048 + wv * 512);
        load_lds16(Bt + (size_t)(n0 + r0) * K + k0 + koff,      Bs + wv * 512);
        load_lds16(Bt + (size_t)(n0 + 64 + r0) * K + k0 + koff, Bs + 2048 + wv * 512);
        __syncthreads();

        bf16x8 af[4], bfr[4];
        #pragma unroll
        for (int i = 0; i < 4; i++) {
            af[i]  = *(const bf16x8*)(As + (wm + i * 16 + l16) * 32 + quad * 8);
            bfr[i] = *(const bf16x8*)(Bs + (wn + i * 16 + l16) * 32 + quad * 8);
        }
        #pragma unroll
        for (int mi = 0; mi < 4; mi++)
            #pragma unroll
            for (int ni = 0; ni < 4; ni++)
                acc[mi][ni] = __builtin_amdgcn_mfma_f32_16x16x32_bf16(
                    af[mi], bfr[ni], acc[mi][ni], 0, 0, 0);
    }

    #pragma unroll
    for (int mi = 0; mi < 4; mi++) {
        int gm = m0 + wm + mi * 16 + quad * 4;
        #pragma unroll
        for (int ni = 0; ni < 4; ni++) {
            int gn = n0 + wn + ni * 16 + l16;
            if (gn < N) {
                float bs = bias1[gn];
                if (bias2) bs += bias2[gn];
                #pragma unroll
                for (int r = 0; r < 4; r++)
                    out[(size_t)(gm + r) * N + gn] = acc[mi][ni][r] + bs;
            }
        }
    }
}

// ---------------------------------------------------------------------------
// Fallback GEMM (round-1): fp32 W with fused conversion, used if ws too small.
__global__ __launch_bounds__(256) void gemm_bf16(
    const bf16_t* __restrict__ A, const float* __restrict__ W1,
    const float* __restrict__ W2, const float* __restrict__ bias1,
    const float* __restrict__ bias2, float* __restrict__ out,
    int M, int N, int K, int K1)
{
    __shared__ __align__(16) bf16_t As[128 * 32];
    __shared__ __align__(16) bf16_t Bs[128 * 40];

    int tid = threadIdx.x;
    int lane = tid & 63, wv = tid >> 6;
    int quad = lane >> 4, l16 = lane & 15;
    int n0 = blockIdx.x * 128, m0 = blockIdx.y * 128;
    int wm = (wv >> 1) * 64, wn = (wv & 1) * 64;

    f32x4 acc[4][4];
    #pragma unroll
    for (int a = 0; a < 4; a++)
        #pragma unroll
        for (int b2 = 0; b2 < 4; b2++) { f32x4 z = {0.f, 0.f, 0.f, 0.f}; acc[a][b2] = z; }

    int brow = tid >> 1, bhalf = tid & 1;
    int gn_l = n0 + brow; if (gn_l >= N) gn_l = N - 1;
    int c0i = wv * 64 + lane, c1i = 256 + wv * 64 + lane;

    for (int k0 = 0; k0 < K; k0 += 32) {
        __syncthreads();
        load_lds16(A + (size_t)(m0 + (c0i >> 2)) * K + k0 + (c0i & 3) * 8, As + wv * 512);
        load_lds16(A + (size_t)(m0 + (c1i >> 2)) * K + k0 + (c1i & 3) * 8, As + 2048 + wv * 512);
        int kk = k0 + bhalf * 16;
        const float* wrow = (kk < K1) ? (W1 + (size_t)gn_l * K1 + kk)
                                      : (W2 + (size_t)gn_l * K1 + (kk - K1));
        float4 f0 = ((const float4*)wrow)[0];
        float4 f1 = ((const float4*)wrow)[1];
        float4 f2 = ((const float4*)wrow)[2];
        float4 f3 = ((const float4*)wrow)[3];
        uint4 p0, p1;
        p0.x = packbf2(f0.x, f0.y); p0.y = packbf2(f0.z, f0.w);
        p0.z = packbf2(f1.x, f1.y); p0.w = packbf2(f1.z, f1.w);
        p1.x = packbf2(f2.x, f2.y); p1.y = packbf2(f2.z, f2.w);
        p1.z = packbf2(f3.x, f3.y); p1.w = packbf2(f3.z, f3.w);
        uint4* bsp = (uint4*)(Bs + brow * 40 + bhalf * 16);
        bsp[0] = p0; bsp[1] = p1;
        __syncthreads();

        bf16x8 af[4], bfr[4];
        #pragma unroll
        for (int i = 0; i < 4; i++) {
            af[i]  = *(const bf16x8*)(As + (wm + i * 16 + l16) * 32 + quad * 8);
            bfr[i] = *(const bf16x8*)(Bs + (wn + i * 16 + l16) * 40 + quad * 8);
        }
        #pragma unroll
        for (int mi = 0; mi < 4; mi++)
            #pragma unroll
            for (int ni = 0; ni < 4; ni++)
                acc[mi][ni] = __builtin_amdgcn_mfma_f32_16x16x32_bf16(
                    af[mi], bfr[ni], acc[mi][ni], 0, 0, 0);
    }

    #pragma unroll
    for (int mi = 0; mi < 4; mi++) {
        int gm = m0 + wm + mi * 16 + quad * 4;
        #pragma unroll
        for (int ni = 0; ni < 4; ni++) {
            int gn = n0 + wn + ni * 16 + l16;
            if (gn < N) {
                float bs = bias1[gn];
                if (bias2) bs += bias2[gn];
                #pragma unroll
                for (int r = 0; r < 4; r++)
                    out[(size_t)(gm + r) * N + gn] = acc[mi][ni][r] + bs;
            }
        }
    }
}

// ---------------------------------------------------------------------------
// K3: LSTM cell elementwise.
__global__ __launch_bounds__(256) void lstm_cell(
    const float* __restrict__ gates, const float* __restrict__ ctx,
    float* __restrict__ h_out, float* __restrict__ c_out,
    uint16_t* __restrict__ h_bf)
{
    int idx = blockIdx.x * 256 + threadIdx.x;
    int b = idx >> 10, e = idx & 1023;
    const float* g = gates + ((size_t)b << 12);
    float iv = g[e], fv = g[e + 1024], gv = g[e + 2048], ov = g[e + 3072];
    iv = 1.f / (1.f + __expf(-iv));
    fv = 1.f / (1.f + __expf(-fv));
    gv = tanhf(gv);
    ov = 1.f / (1.f + __expf(-ov));
    float c = fv * ctx[idx] + iv * gv;
    float h = ov * tanhf(c);
    c_out[idx] = c;
    h_out[idx] = h;
    h_bf[idx] = f2bf(h);
}

// ---------------------------------------------------------------------------
extern "C" void kernel_launch(void* const* d_in, const int* in_sizes, int n_in,
                              void* d_out, int out_size, void* d_ws, size_t ws_size,
                              hipStream_t stream)
{
    const int*   ts     = (const int*)d_in[0];
    const float* enc    = (const float*)d_in[1];
    const float* h0     = (const float*)d_in[2];
    const void*  mask   = d_in[4];
    const float* emb    = (const float*)d_in[6];
    const float* w_ih   = (const float*)d_in[7];
    const float* w_hh   = (const float*)d_in[8];
    const float* b_ih   = (const float*)d_in[9];
    const float* b_hh   = (const float*)d_in[10];
    const float* w_proj = (const float*)d_in[11];
    const float* b_proj = (const float*)d_in[12];
    float* out = (float*)d_out;

    // ws layout
    char* ws = (char*)d_ws;
    size_t off = 0;
    int*      mode   = (int*)(ws + off);      off += 256;
    float*    ctx_f  = (float*)(ws + off);    off += (size_t)B_N * E_N * 4;       // 2 MB
    bf16_t*   a_lstm = (bf16_t*)(ws + off);   off += (size_t)B_N * 2048 * 2;      // 2 MB
    uint16_t* h_bf   = (uint16_t*)(ws + off); off += (size_t)B_N * E_N * 2;       // 1 MB
    float*    normed = (float*)(ws + off);    off += (size_t)B_N * 64 * 4;        // 128 KB
    uint16_t* wcat   = (uint16_t*)(ws + off); off += (size_t)4096 * 2048 * 2;     // 16 MB
    uint16_t* wproj  = (uint16_t*)(ws + off); off += (size_t)V_PAD * 1024 * 2;    // 102.5 MB
    bool big_ws = (ws_size >= off);

    float* gates = out;                                  // reuse logits region
    float* h_out = out + (size_t)B_N * V_N;
    float* c_out = h_out + (size_t)B_N * E_N;

    detect_mask_mode<<<1, 256, 0, stream>>>((const uint32_t*)mask, mode);
    energy_kernel<<<B_N, 256, 0, stream>>>(enc, h0, mask, mode, normed);
    ctx_kernel<<<dim3(B_N, 4), 256, 0, stream>>>(enc, normed, ts, emb, ctx_f, a_lstm);

    if (big_ws) {
        convert_cat<<<4096, 256, 0, stream>>>(w_ih, w_hh, wcat);
        convert_proj<<<(V_PAD * 1024 / 8) / 256, 256, 0, stream>>>(w_proj, wproj);
        // gates = [words|ctx] @ wcat^T + b_ih + b_hh   (M=512, N=4096, K=2048)
        gemm_bt<<<dim3(4, 4096 / 128), 256, 0, stream>>>(
            a_lstm, (const bf16_t*)wcat, b_ih, b_hh, gates, B_N, 4096, 2048);
        lstm_cell<<<(B_N * E_N) / 256, 256, 0, stream>>>(gates, ctx_f, h_out, c_out, h_bf);
        // logits = h_new @ wproj^T + b_proj             (M=512, N=50000, K=1024)
        gemm_bt<<<dim3(4, V_PAD / 128), 256, 0, stream>>>(
            (const bf16_t*)h_bf, (const bf16_t*)wproj, b_proj, nullptr, out, B_N, V_N, 1024);
    } else {
        gemm_bf16<<<dim3(4096 / 128, B_N / 128), 256, 0, stream>>>(
            a_lstm, w_ih, w_hh, b_ih, b_hh, gates, B_N, 4096, 2048, 1024);
        lstm_cell<<<(B_N * E_N) / 256, 256, 0, stream>>>(gates, ctx_f, h_out, c_out, h_bf);
        gemm_bf16<<<dim3((V_N + 127) / 128, B_N / 128), 256, 0, stream>>>(
            (const bf16_t*)h_bf, w_proj, w_proj, b_proj, nullptr, out, B_N, V_N, 1024, 1024);
    }
}